// Round 12
// baseline (308.317 us; speedup 1.0000x reference)
//
#include <hip/hip_runtime.h>

#define N_NODES 50000
#define N_EDGES 800000
#define D 64          // D_IN == D_OUT
#define ED 32         // EDGE_DIM
#define BN_EPS 1e-5f

#define NBKT 250      // buckets
#define NPB  200      // nodes per bucket (250*200 = 50000)
#define NB_SC 500     // blocks for bin_scatter
#define EPB  1600     // edges per bin block (500*1600 = 800000)
#define CAP  4096     // pack capacity per bucket (mean 3200, +15 sigma)

// ---- workspace layout (32-bit word indices) -------------------------------
#define WS_SUMS     0
#define WS_SUMSQ    64
#define WS_RESV     128                       // 256 ints (250 used)
#define WS_ZERO_END 384                       // memset [0, here) = 1.5 KB
#define WS_OFF      384                       // 50004 ints
#define WS_PACK     50388                     // uint2 x 250*4096 (8B ok, even)
#define WS_SRC2     (WS_PACK + 2 * NBKT * CAP)   // 2098388 (8B ok)
#define WS_H        (WS_SRC2 + 2 * N_EDGES)   // 3698388 (16B ok)
#define WS_WC       (WS_H + N_NODES * D)      // 6898388 (16B ok)
#define WS_BEC      (WS_WC + ED * D)          // 6900436
// total ~ 27.6 MB (ws proved >= 68 MB)

#define N_BLK ((N_NODES + 63) / 64)   // 782 tiles

// ---------------------------------------------------------------------------
// Fold edge MLP into main GEMM: wc = We@W1 [32x64], bec = be@W1 [64]
__global__ __launch_bounds__(256) void foldw_kernel(
    const float* __restrict__ We, const float* __restrict__ W1,
    const float* __restrict__ be, float* __restrict__ wc, float* __restrict__ bec)
{
    const int idx = blockIdx.x * 256 + threadIdx.x;
    if (idx < ED * D) {
        const int j = idx >> 6, f = idx & 63;
        float a = 0.f;
        for (int k = 0; k < D; ++k) a += We[j * D + k] * W1[k * D + f];
        wc[idx] = a;
    }
    if (idx < D) {
        float a = 0.f;
        for (int k = 0; k < D; ++k) a += be[k] * W1[k * D + idx];
        bec[idx] = a;
    }
}

// ---------------------------------------------------------------------------
// Single-pass bucket scatter; chunk staged in LDS once (no global re-reads).
// ONE resv atomic per bucket reserves a run in the bucket's fixed segment.
__global__ __launch_bounds__(256) void bin_scatter_kernel(
    const int* __restrict__ ei, int* __restrict__ resv, uint2* __restrict__ pack)
{
    __shared__ int hist[NBKT], seg[NBKT], lcur[NBKT];
    __shared__ int sSrc[EPB], sDst[EPB];      // 12.8 KB
    const int t = threadIdx.x;
    if (t < NBKT) { hist[t] = 0; lcur[t] = 0; }
    const int e0 = blockIdx.x * EPB;
    for (int i = t; i < EPB; i += 256) {
        sSrc[i] = ei[e0 + i];
        sDst[i] = ei[N_EDGES + e0 + i];
    }
    __syncthreads();
    for (int i = t; i < EPB; i += 256)        // phase A: chunk histogram
        atomicAdd(&hist[sDst[i] / NPB], 1);
    __syncthreads();
    if (t < NBKT) seg[t] = t * CAP + atomicAdd(&resv[t], hist[t]);
    __syncthreads();
    for (int i = t; i < EPB; i += 256) {      // phase B: place into segment
        const int d = sDst[i];
        const int bkt = d / NPB;
        const int r = atomicAdd(&lcur[bkt], 1);
        pack[seg[bkt] + r] = make_uint2(((unsigned)d << 16) | (unsigned)sSrc[i],
                                        (unsigned)(e0 + i));
    }
}

// ---------------------------------------------------------------------------
// One block per bucket (512 thr). Scan of resv -> CSR bases; per-node
// histogram + scan -> off[]; final placement of int2 (eid, src).
__global__ __launch_bounds__(512) void bucket_place_kernel(
    const int* __restrict__ resv, const uint2* __restrict__ pack,
    int* __restrict__ off, int2* __restrict__ sorted)
{
    __shared__ int sA[256], sB[256];
    __shared__ int cnt[NPB], lcur[NPB];
    __shared__ int pA[256], pB[256];
    __shared__ int sBase, sNE;
    const int t = threadIdx.x;
    const int j = blockIdx.x;
    if (t < 256) sA[t] = (t < NBKT) ? resv[t] : 0;
    if (t < NPB) { cnt[t] = 0; lcur[t] = 0; }
    __syncthreads();
    int* cur = sA; int* nxt = sB;
    for (int o = 1; o < 256; o <<= 1) {       // bucket bases (inclusive scan)
        if (t < 256) nxt[t] = cur[t] + (t >= o ? cur[t - o] : 0);
        __syncthreads();
        int* tmp = cur; cur = nxt; nxt = tmp;
    }
    if (t == 0) { sBase = (j == 0) ? 0 : cur[j - 1]; sNE = resv[j]; }
    __syncthreads();
    const int base = sBase, nE = sNE;
    const uint2* pp = pack + (size_t)j * CAP;

    for (int i = t; i < nE; i += 512)         // per-node histogram
        atomicAdd(&cnt[(int)(pp[i].x >> 16) - j * NPB], 1);
    __syncthreads();
    if (t < 256) pA[t] = (t < NPB) ? cnt[t] : 0;
    __syncthreads();
    int* c2 = pA; int* n2 = pB;
    for (int o = 1; o < 256; o <<= 1) {       // per-node inclusive scan
        if (t < 256) n2[t] = c2[t] + (t >= o ? c2[t - o] : 0);
        __syncthreads();
        int* tmp = c2; c2 = n2; n2 = tmp;
    }
    if (t < NPB) {                            // n2 := exclusive starts; off[]
        const int excl = (t == 0) ? 0 : c2[t - 1];
        n2[t] = excl;
        off[j * NPB + t] = base + excl;
    }
    if (j == NBKT - 1 && t == 0) off[N_NODES] = N_EDGES;
    __syncthreads();
    for (int i = t; i < nE; i += 512) {       // final placement
        const uint2 w = pp[i];
        const int dl = (int)(w.x >> 16) - j * NPB;
        const int r = atomicAdd(&lcur[dl], 1);
        sorted[base + n2[dl] + r] = make_int2((int)w.y, (int)(w.x & 0xffffu));
    }
}

// ---------------------------------------------------------------------------
// FUSED gather + MLP1. Block = 1024 thr (16 waves) owns a 64-node tile.
// Phase 1 (all waves): verbatim agg gather, results land in LDS As.
// Phase 2 (waves 0-3): verbatim mlp1g GEMM from As (staging deleted).
// Eliminates the pre/aggEA HBM round-trip (38.4 MB) and one launch; GEMM of
// one block overlaps gather of the co-resident block (2 blocks/CU, 32 w/CU).
__global__ __launch_bounds__(1024) void agg_mlp1_kernel(
    const float* __restrict__ x, const float* __restrict__ ea,
    const int* __restrict__ off, const int2* __restrict__ sorted,
    const float* __restrict__ W1, const float* __restrict__ wc,
    const float* __restrict__ bec, const float* __restrict__ b1,
    float* __restrict__ h, float* __restrict__ sums, float* __restrict__ sumsq)
{
    __shared__ float As[64 * 100];   // [node][k] k:0-63 pre, 64-95 aggEA (25.6 KB)
    __shared__ float Bs[96 * 64];    // [k][f] (24.6 KB; reused for BN reduce)
    __shared__ float4 sb1v[16];
    __shared__ float4 sbecv[16];
    __shared__ float sDeg[64];
    const int tid = threadIdx.x;
    const int base = blockIdx.x * 64;

    for (int i = tid; i < 64 * 16; i += 1024)
        ((float4*)Bs)[i] = ((const float4*)W1)[i];
    for (int i = tid; i < 32 * 16; i += 1024)
        ((float4*)Bs)[64 * 16 + i] = ((const float4*)wc)[i];
    if (tid < 16)      sb1v[tid] = ((const float4*)b1)[tid];
    else if (tid < 32) sbecv[tid - 16] = ((const float4*)bec)[tid - 16];

    // ---- phase 1: gather (verbatim agg loop; LDS destination) ----
    const int f = tid & 63;
    const int w = tid >> 6;
    const int fe = f & 31;
    const bool lo = (f < 32);
    #pragma unroll
    for (int i = 0; i < 4; ++i) {
        const int nl = w * 4 + i;             // 0..63, wave-uniform
        const int node = base + nl;
        float s = 0.f, ax = 0.f, ay = 0.f;
        int n = 0;
        if (node < N_NODES) {
            const int start = __builtin_amdgcn_readfirstlane(off[node]);
            n = __builtin_amdgcn_readfirstlane(off[node + 1]) - start;
            const int2* sp = sorted + start;
            s = x[(size_t)node * D + f];
            int it = 0;
            if (n >= 8) {
                int2 c0 = sp[0], c1 = sp[1], c2 = sp[2], c3 = sp[3];
                int2 c4 = sp[4], c5 = sp[5], c6 = sp[6], c7 = sp[7];
                for (; it + 16 <= n; it += 8) {
                    const int2 n0 = sp[it + 8],  n1 = sp[it + 9];
                    const int2 n2 = sp[it + 10], n3 = sp[it + 11];
                    const int2 n4 = sp[it + 12], n5 = sp[it + 13];
                    const int2 n6 = sp[it + 14], n7 = sp[it + 15];
                    s += x[(size_t)c0.y * D + f]; s += x[(size_t)c1.y * D + f];
                    s += x[(size_t)c2.y * D + f]; s += x[(size_t)c3.y * D + f];
                    s += x[(size_t)c4.y * D + f]; s += x[(size_t)c5.y * D + f];
                    s += x[(size_t)c6.y * D + f]; s += x[(size_t)c7.y * D + f];
                    ax += ea[(size_t)(lo ? c0.x : c1.x) * ED + fe];
                    ax += ea[(size_t)(lo ? c2.x : c3.x) * ED + fe];
                    ay += ea[(size_t)(lo ? c4.x : c5.x) * ED + fe];
                    ay += ea[(size_t)(lo ? c6.x : c7.x) * ED + fe];
                    c0 = n0; c1 = n1; c2 = n2; c3 = n3;
                    c4 = n4; c5 = n5; c6 = n6; c7 = n7;
                }
                s += x[(size_t)c0.y * D + f]; s += x[(size_t)c1.y * D + f];
                s += x[(size_t)c2.y * D + f]; s += x[(size_t)c3.y * D + f];
                s += x[(size_t)c4.y * D + f]; s += x[(size_t)c5.y * D + f];
                s += x[(size_t)c6.y * D + f]; s += x[(size_t)c7.y * D + f];
                ax += ea[(size_t)(lo ? c0.x : c1.x) * ED + fe];
                ax += ea[(size_t)(lo ? c2.x : c3.x) * ED + fe];
                ay += ea[(size_t)(lo ? c4.x : c5.x) * ED + fe];
                ay += ea[(size_t)(lo ? c6.x : c7.x) * ED + fe];
                it += 8;
            }
            for (; it < n; ++it) {            // tail: 0..7 edges
                const int2 p = sp[it];
                s += x[(size_t)p.y * D + f];
                if (lo) ax += ea[(size_t)p.x * ED + fe];
            }
        }
        As[nl * 100 + f] = s;
        ax += ay;
        ax += __shfl_xor(ax, 32);             // even-edge + odd-edge halves
        if (lo) As[nl * 100 + 64 + fe] = ax;
        if (f == 0) sDeg[nl] = (float)n;
    }
    __syncthreads();

    // ---- phase 2: GEMM (waves 0-3 only; verbatim mlp1g compute) ----
    float4 ps = make_float4(0.f, 0.f, 0.f, 0.f);
    float4 pq = make_float4(0.f, 0.f, 0.f, 0.f);
    const int tx = tid & 15, ty = (tid >> 4) & 15;
    if (tid < 256) {
        const int r0 = ty * 4;
        const float4 bb = sb1v[tx];
        const float4 bc = sbecv[tx];
        float4 acc0, acc1, acc2, acc3;
        acc0.x = bb.x + sDeg[r0+0]*bc.x; acc0.y = bb.y + sDeg[r0+0]*bc.y;
        acc0.z = bb.z + sDeg[r0+0]*bc.z; acc0.w = bb.w + sDeg[r0+0]*bc.w;
        acc1.x = bb.x + sDeg[r0+1]*bc.x; acc1.y = bb.y + sDeg[r0+1]*bc.y;
        acc1.z = bb.z + sDeg[r0+1]*bc.z; acc1.w = bb.w + sDeg[r0+1]*bc.w;
        acc2.x = bb.x + sDeg[r0+2]*bc.x; acc2.y = bb.y + sDeg[r0+2]*bc.y;
        acc2.z = bb.z + sDeg[r0+2]*bc.z; acc2.w = bb.w + sDeg[r0+2]*bc.w;
        acc3.x = bb.x + sDeg[r0+3]*bc.x; acc3.y = bb.y + sDeg[r0+3]*bc.y;
        acc3.z = bb.z + sDeg[r0+3]*bc.z; acc3.w = bb.w + sDeg[r0+3]*bc.w;

        for (int k4 = 0; k4 < 24; ++k4) {
            const int k = k4 * 4;
            const float4 a0 = *(const float4*)&As[(r0+0)*100 + k];
            const float4 a1 = *(const float4*)&As[(r0+1)*100 + k];
            const float4 a2 = *(const float4*)&As[(r0+2)*100 + k];
            const float4 a3 = *(const float4*)&As[(r0+3)*100 + k];
            const float4 w0 = *(const float4*)&Bs[(k+0)*64 + tx*4];
            const float4 w1v = *(const float4*)&Bs[(k+1)*64 + tx*4];
            const float4 w2v = *(const float4*)&Bs[(k+2)*64 + tx*4];
            const float4 w3v = *(const float4*)&Bs[(k+3)*64 + tx*4];
            acc0.x += a0.x*w0.x + a0.y*w1v.x + a0.z*w2v.x + a0.w*w3v.x;
            acc0.y += a0.x*w0.y + a0.y*w1v.y + a0.z*w2v.y + a0.w*w3v.y;
            acc0.z += a0.x*w0.z + a0.y*w1v.z + a0.z*w2v.z + a0.w*w3v.z;
            acc0.w += a0.x*w0.w + a0.y*w1v.w + a0.z*w2v.w + a0.w*w3v.w;
            acc1.x += a1.x*w0.x + a1.y*w1v.x + a1.z*w2v.x + a1.w*w3v.x;
            acc1.y += a1.x*w0.y + a1.y*w1v.y + a1.z*w2v.y + a1.w*w3v.y;
            acc1.z += a1.x*w0.z + a1.y*w1v.z + a1.z*w2v.z + a1.w*w3v.z;
            acc1.w += a1.x*w0.w + a1.y*w1v.w + a1.z*w2v.w + a1.w*w3v.w;
            acc2.x += a2.x*w0.x + a2.y*w1v.x + a2.z*w2v.x + a2.w*w3v.x;
            acc2.y += a2.x*w0.y + a2.y*w1v.y + a2.z*w2v.y + a2.w*w3v.y;
            acc2.z += a2.x*w0.z + a2.y*w1v.z + a2.z*w2v.z + a2.w*w3v.z;
            acc2.w += a2.x*w0.w + a2.y*w1v.w + a2.z*w2v.w + a2.w*w3v.w;
            acc3.x += a3.x*w0.x + a3.y*w1v.x + a3.z*w2v.x + a3.w*w3v.x;
            acc3.y += a3.x*w0.y + a3.y*w1v.y + a3.z*w2v.y + a3.w*w3v.y;
            acc3.z += a3.x*w0.z + a3.y*w1v.z + a3.z*w2v.z + a3.w*w3v.z;
            acc3.w += a3.x*w0.w + a3.y*w1v.w + a3.z*w2v.w + a3.w*w3v.w;
        }

        const int n0 = base + r0;
        if (n0 + 0 < N_NODES) {
            ((float4*)h)[(size_t)(n0+0)*16 + tx] = acc0;
            ps.x += acc0.x; ps.y += acc0.y; ps.z += acc0.z; ps.w += acc0.w;
            pq.x += acc0.x*acc0.x; pq.y += acc0.y*acc0.y;
            pq.z += acc0.z*acc0.z; pq.w += acc0.w*acc0.w;
        }
        if (n0 + 1 < N_NODES) {
            ((float4*)h)[(size_t)(n0+1)*16 + tx] = acc1;
            ps.x += acc1.x; ps.y += acc1.y; ps.z += acc1.z; ps.w += acc1.w;
            pq.x += acc1.x*acc1.x; pq.y += acc1.y*acc1.y;
            pq.z += acc1.z*acc1.z; pq.w += acc1.w*acc1.w;
        }
        if (n0 + 2 < N_NODES) {
            ((float4*)h)[(size_t)(n0+2)*16 + tx] = acc2;
            ps.x += acc2.x; ps.y += acc2.y; ps.z += acc2.z; ps.w += acc2.w;
            pq.x += acc2.x*acc2.x; pq.y += acc2.y*acc2.y;
            pq.z += acc2.z*acc2.z; pq.w += acc2.w*acc2.w;
        }
        if (n0 + 3 < N_NODES) {
            ((float4*)h)[(size_t)(n0+3)*16 + tx] = acc3;
            ps.x += acc3.x; ps.y += acc3.y; ps.z += acc3.z; ps.w += acc3.w;
            pq.x += acc3.x*acc3.x; pq.y += acc3.y*acc3.y;
            pq.z += acc3.z*acc3.z; pq.w += acc3.w*acc3.w;
        }
    }
    __syncthreads();                  // all Bs GEMM reads done
    float* sS = Bs;                   // reuse B-tile LDS for BN reduction
    float* sQ = Bs + 1024;
    if (tid < 256) {
        sS[ty*64 + tx*4 + 0] = ps.x; sS[ty*64 + tx*4 + 1] = ps.y;
        sS[ty*64 + tx*4 + 2] = ps.z; sS[ty*64 + tx*4 + 3] = ps.w;
        sQ[ty*64 + tx*4 + 0] = pq.x; sQ[ty*64 + tx*4 + 1] = pq.y;
        sQ[ty*64 + tx*4 + 2] = pq.z; sQ[ty*64 + tx*4 + 3] = pq.w;
    }
    __syncthreads();
    if (tid < 64) {
        float s = 0.f, q = 0.f;
        #pragma unroll
        for (int r = 0; r < 16; ++r) { s += sS[r*64 + tid]; q += sQ[r*64 + tid]; }
        unsafeAtomicAdd(&sums[tid], s);
        unsafeAtomicAdd(&sumsq[tid], q);
    }
}

// ---------------------------------------------------------------------------
// MLP2 as tiled GEMM: out = relu(h*sc+sh) @ W2 + b2 (BN applied at A-staging)
__global__ __launch_bounds__(256) void mlp2g_kernel(
    const float* __restrict__ h, const float* __restrict__ W2,
    const float* __restrict__ b2, const float* __restrict__ sums,
    const float* __restrict__ sumsq, const float* __restrict__ gamma,
    const float* __restrict__ beta, float* __restrict__ out)
{
    __shared__ float As[64 * 68];
    __shared__ float Bs[64 * 64];
    __shared__ float4 sb2v[16];
    __shared__ float4 sscv[16];
    __shared__ float4 sshv[16];
    const int tid = threadIdx.x;
    const int base = blockIdx.x * 64;

    for (int i = tid; i < 64 * 16; i += 256)
        ((float4*)Bs)[i] = ((const float4*)W2)[i];
    if (tid < 16) sb2v[tid] = ((const float4*)b2)[tid];
    if (tid < 64) {
        const float inv_n = 1.0f / (float)N_NODES;
        const float mean = sums[tid] * inv_n;
        const float var  = sumsq[tid] * inv_n - mean * mean;   // biased, like jnp.var
        const float sc   = gamma[tid] * rsqrtf(var + BN_EPS);
        ((float*)sscv)[tid] = sc;
        ((float*)sshv)[tid] = beta[tid] - mean * sc;
    }
    __syncthreads();

    #pragma unroll
    for (int r = 0; r < 4; ++r) {
        const int idx = tid + 256 * r;
        const int nl = idx >> 4, c4 = idx & 15;
        const bool v = (base + nl) < N_NODES;
        const float4 t = v ? ((const float4*)h)[(size_t)(base + nl) * 16 + c4]
                           : make_float4(0.f, 0.f, 0.f, 0.f);
        const float4 c = sscv[c4];
        const float4 s = sshv[c4];
        float4 rv;
        rv.x = fmaxf(t.x * c.x + s.x, 0.f);
        rv.y = fmaxf(t.y * c.y + s.y, 0.f);
        rv.z = fmaxf(t.z * c.z + s.z, 0.f);
        rv.w = fmaxf(t.w * c.w + s.w, 0.f);
        *(float4*)&As[nl * 68 + c4 * 4] = rv;
    }
    __syncthreads();

    const int tx = tid & 15, ty = tid >> 4;
    const int r0 = ty * 4;
    const float4 bb = sb2v[tx];
    float4 acc0 = bb, acc1 = bb, acc2 = bb, acc3 = bb;

    for (int k4 = 0; k4 < 16; ++k4) {
        const int k = k4 * 4;
        const float4 a0 = *(const float4*)&As[(r0+0)*68 + k];
        const float4 a1 = *(const float4*)&As[(r0+1)*68 + k];
        const float4 a2 = *(const float4*)&As[(r0+2)*68 + k];
        const float4 a3 = *(const float4*)&As[(r0+3)*68 + k];
        const float4 w0 = *(const float4*)&Bs[(k+0)*64 + tx*4];
        const float4 w1v = *(const float4*)&Bs[(k+1)*64 + tx*4];
        const float4 w2v = *(const float4*)&Bs[(k+2)*64 + tx*4];
        const float4 w3v = *(const float4*)&Bs[(k+3)*64 + tx*4];
        acc0.x += a0.x*w0.x + a0.y*w1v.x + a0.z*w2v.x + a0.w*w3v.x;
        acc0.y += a0.x*w0.y + a0.y*w1v.y + a0.z*w2v.y + a0.w*w3v.y;
        acc0.z += a0.x*w0.z + a0.y*w1v.z + a0.z*w2v.z + a0.w*w3v.z;
        acc0.w += a0.x*w0.w + a0.y*w1v.w + a0.z*w2v.w + a0.w*w3v.w;
        acc1.x += a1.x*w0.x + a1.y*w1v.x + a1.z*w2v.x + a1.w*w3v.x;
        acc1.y += a1.x*w0.y + a1.y*w1v.y + a1.z*w2v.y + a1.w*w3v.y;
        acc1.z += a1.x*w0.z + a1.y*w1v.z + a1.z*w2v.z + a1.w*w3v.z;
        acc1.w += a1.x*w0.w + a1.y*w1v.w + a1.z*w2v.w + a1.w*w3v.w;
        acc2.x += a2.x*w0.x + a2.y*w1v.x + a2.z*w2v.x + a2.w*w3v.x;
        acc2.y += a2.x*w0.y + a2.y*w1v.y + a2.z*w2v.y + a2.w*w3v.y;
        acc2.z += a2.x*w0.z + a2.y*w1v.z + a2.z*w2v.z + a2.w*w3v.z;
        acc2.w += a2.x*w0.w + a2.y*w1v.w + a2.z*w2v.w + a2.w*w3v.w;
        acc3.x += a3.x*w0.x + a3.y*w1v.x + a3.z*w2v.x + a3.w*w3v.x;
        acc3.y += a3.x*w0.y + a3.y*w1v.y + a3.z*w2v.y + a3.w*w3v.y;
        acc3.z += a3.x*w0.z + a3.y*w1v.z + a3.z*w2v.z + a3.w*w3v.z;
        acc3.w += a3.x*w0.w + a3.y*w1v.w + a3.z*w2v.w + a3.w*w3v.w;
    }

    const int n0 = base + r0;
    if (n0 + 0 < N_NODES) ((float4*)out)[(size_t)(n0+0)*16 + tx] = acc0;
    if (n0 + 1 < N_NODES) ((float4*)out)[(size_t)(n0+1)*16 + tx] = acc1;
    if (n0 + 2 < N_NODES) ((float4*)out)[(size_t)(n0+2)*16 + tx] = acc2;
    if (n0 + 3 < N_NODES) ((float4*)out)[(size_t)(n0+3)*16 + tx] = acc3;
}

// ---------------------------------------------------------------------------
extern "C" void kernel_launch(void* const* d_in, const int* in_sizes, int n_in,
                              void* d_out, int out_size, void* d_ws, size_t ws_size,
                              hipStream_t stream) {
    const float* x     = (const float*)d_in[0];
    const int*   ei    = (const int*)  d_in[1];   // [2, E] int32
    const float* ea    = (const float*)d_in[2];
    const float* We    = (const float*)d_in[3];
    const float* be    = (const float*)d_in[4];
    const float* W1    = (const float*)d_in[5];
    const float* b1    = (const float*)d_in[6];
    const float* gamma = (const float*)d_in[7];
    const float* beta  = (const float*)d_in[8];
    const float* W2    = (const float*)d_in[9];
    const float* b2    = (const float*)d_in[10];

    float* ws      = (float*)d_ws;
    float* sums    = ws + WS_SUMS;
    float* sumsq   = ws + WS_SUMSQ;
    int*   resv    = (int*)(ws + WS_RESV);
    int*   off     = (int*)(ws + WS_OFF);
    uint2* pack    = (uint2*)(ws + WS_PACK);
    int2*  sorted2 = (int2*)(ws + WS_SRC2);
    float* h       = ws + WS_H;
    float* wcbuf   = ws + WS_WC;
    float* becbuf  = ws + WS_BEC;

    hipMemsetAsync(ws, 0, (size_t)WS_ZERO_END * sizeof(float), stream);

    foldw_kernel       <<<8, 256, 0, stream>>>(We, W1, be, wcbuf, becbuf);
    bin_scatter_kernel <<<NB_SC, 256, 0, stream>>>(ei, resv, pack);
    bucket_place_kernel<<<NBKT, 512, 0, stream>>>(resv, pack, off, sorted2);
    agg_mlp1_kernel    <<<N_BLK, 1024, 0, stream>>>(x, ea, off, sorted2, W1, wcbuf,
                                                    becbuf, b1, h, sums, sumsq);
    mlp2g_kernel       <<<N_BLK, 256, 0, stream>>>(h, W2, b2, sums, sumsq,
                                                   gamma, beta, (float*)d_out);
}

// Round 13
// 282.693 us; speedup vs baseline: 1.0906x; 1.0906x over previous
//
#include <hip/hip_runtime.h>

#define N_NODES 50000
#define N_EDGES 800000
#define D 64          // D_IN == D_OUT
#define ED 32         // EDGE_DIM
#define BN_EPS 1e-5f

#define NBKT 500      // buckets
#define NPB  100      // nodes per bucket (500*100 = 50000)
#define NB_SC 500     // blocks for bin_scatter (+8 foldw blocks appended)
#define EPB  1600     // edges per bin block (500*1600 = 800000)
#define CAP  2048     // pack capacity per bucket (mean 1600, +11 sigma)

// ---- workspace layout (32-bit word indices) -------------------------------
#define WS_SUMS     0
#define WS_SUMSQ    64
#define WS_RESV     128                       // 512 ints (500 used)
#define WS_ZERO_END 640                       // memset [0, here) = 2.5 KB
#define WS_OFF      640                       // 50004 ints
#define WS_PACK     50644                     // uint2 x 500*2048 (8B ok)
#define WS_SRC2     (WS_PACK + 2 * NBKT * CAP)   // 2098644 (8B ok)
#define WS_H        (WS_SRC2 + 2 * N_EDGES)   // 3698644 (16B ok)
#define WS_WC       (WS_H + N_NODES * D)      // 6898644 (16B ok)
#define WS_BEC      (WS_WC + ED * D)          // 6900692
// total ~ 27.6 MB (ws proved >= 68 MB)

#define N_BLK ((N_NODES + 63) / 64)   // 782 GEMM tiles

// ---------------------------------------------------------------------------
// Single-pass bucket scatter (blocks 0..NB_SC-1) + foldw (blocks NB_SC..+7).
// Scatter: chunk staged in LDS; per-block LDS histogram; ONE resv atomic per
// bucket reserves a run in the bucket's fixed segment (j*CAP).
// Foldw: wc = We@W1 [32x64], bec = be@W1 [64] (independent work, merged to
// save a dispatch).
__global__ __launch_bounds__(256) void bin_scatter_kernel(
    const int* __restrict__ ei, int* __restrict__ resv, uint2* __restrict__ pack,
    const float* __restrict__ We, const float* __restrict__ W1,
    const float* __restrict__ be, float* __restrict__ wc, float* __restrict__ bec)
{
    const int t = threadIdx.x;
    if (blockIdx.x >= NB_SC) {                // ---- foldw tail blocks ----
        const int idx = (blockIdx.x - NB_SC) * 256 + t;
        if (idx < ED * D) {
            const int j = idx >> 6, f = idx & 63;
            float a = 0.f;
            for (int k = 0; k < D; ++k) a += We[j * D + k] * W1[k * D + f];
            wc[idx] = a;
        }
        if (idx < D) {
            float a = 0.f;
            for (int k = 0; k < D; ++k) a += be[k] * W1[k * D + idx];
            bec[idx] = a;
        }
        return;
    }
    __shared__ int hist[NBKT], seg[NBKT], lcur[NBKT];
    __shared__ int sSrc[EPB], sDst[EPB];      // 12.8 KB
    for (int i = t; i < NBKT; i += 256) { hist[i] = 0; lcur[i] = 0; }
    const int e0 = blockIdx.x * EPB;
    for (int i = t; i < EPB; i += 256) {
        sSrc[i] = ei[e0 + i];
        sDst[i] = ei[N_EDGES + e0 + i];
    }
    __syncthreads();
    for (int i = t; i < EPB; i += 256)        // phase A: chunk histogram
        atomicAdd(&hist[sDst[i] / NPB], 1);
    __syncthreads();
    for (int i = t; i < NBKT; i += 256)
        seg[i] = i * CAP + atomicAdd(&resv[i], hist[i]);
    __syncthreads();
    for (int i = t; i < EPB; i += 256) {      // phase B: place into segment
        const int d = sDst[i];
        const int bkt = d / NPB;
        const int r = atomicAdd(&lcur[bkt], 1);
        pack[seg[bkt] + r] = make_uint2(((unsigned)d << 16) | (unsigned)sSrc[i],
                                        (unsigned)(e0 + i));
    }
}

// ---------------------------------------------------------------------------
// One block per bucket (512 thr). Scan of resv -> CSR bases; per-node
// histogram + scan -> off[]; final placement of int2 (eid, src).
__global__ __launch_bounds__(512) void bucket_place_kernel(
    const int* __restrict__ resv, const uint2* __restrict__ pack,
    int* __restrict__ off, int2* __restrict__ sorted)
{
    __shared__ int sA[512], sB[512];
    __shared__ int cnt[NPB], lcur[NPB];
    __shared__ int pA[128], pB[128];
    __shared__ int sBase, sNE;
    const int t = threadIdx.x;
    const int j = blockIdx.x;
    sA[t] = (t < NBKT) ? resv[t] : 0;
    if (t < NPB) { cnt[t] = 0; lcur[t] = 0; }
    __syncthreads();
    int* cur = sA; int* nxt = sB;
    for (int o = 1; o < 512; o <<= 1) {       // bucket bases (inclusive scan)
        nxt[t] = cur[t] + (t >= o ? cur[t - o] : 0);
        __syncthreads();
        int* tmp = cur; cur = nxt; nxt = tmp;
    }
    if (t == 0) { sBase = (j == 0) ? 0 : cur[j - 1]; sNE = resv[j]; }
    __syncthreads();
    const int base = sBase, nE = sNE;
    const uint2* pp = pack + (size_t)j * CAP;

    for (int i = t; i < nE; i += 512)         // per-node histogram
        atomicAdd(&cnt[(int)(pp[i].x >> 16) - j * NPB], 1);
    __syncthreads();
    if (t < 128) pA[t] = (t < NPB) ? cnt[t] : 0;
    __syncthreads();
    int* c2 = pA; int* n2 = pB;
    for (int o = 1; o < 128; o <<= 1) {       // per-node inclusive scan
        if (t < 128) n2[t] = c2[t] + (t >= o ? c2[t - o] : 0);
        __syncthreads();
        int* tmp = c2; c2 = n2; n2 = tmp;
    }
    if (t < NPB) {                            // n2 := exclusive starts; off[]
        const int excl = (t == 0) ? 0 : c2[t - 1];
        n2[t] = excl;
        off[j * NPB + t] = base + excl;
    }
    if (j == NBKT - 1 && t == 0) off[N_NODES] = N_EDGES;
    __syncthreads();
    for (int i = t; i < nE; i += 512) {       // final placement
        const uint2 w = pp[i];
        const int dl = (int)(w.x >> 16) - j * NPB;
        const int r = atomicAdd(&lcur[dl], 1);
        sorted[base + n2[dl] + r] = make_int2((int)w.y, (int)(w.x & 0xffffu));
    }
}

// ---------------------------------------------------------------------------
// Pure gather, no LDS -> full occupancy. Per node (wave):
//   pre->As handled downstream; here writes pre & aggEA equivalents to LDS-free
//   buffers consumed by mlp1g. (Verbatim round-9/11 kernel.)
__global__ __launch_bounds__(256) void agg_kernel(
    const float* __restrict__ x, const float* __restrict__ ea,
    const int* __restrict__ off, const int2* __restrict__ sorted,
    float* __restrict__ pre, float* __restrict__ aggEA)
{
    const int f = threadIdx.x & 63;
    const int w = threadIdx.x >> 6;
    const int fe = f & 31;
    const bool lo = (f < 32);
    const int nwv = gridDim.x * 4;
    for (int node = blockIdx.x * 4 + w; node < N_NODES; node += nwv) {
        const int start = __builtin_amdgcn_readfirstlane(off[node]);
        const int n     = __builtin_amdgcn_readfirstlane(off[node + 1]) - start;
        const int2* sp = sorted + start;
        float s = x[(size_t)node * D + f];
        float ax = 0.f, ay = 0.f;
        int it = 0;
        if (n >= 8) {
            int2 c0 = sp[0], c1 = sp[1], c2 = sp[2], c3 = sp[3];
            int2 c4 = sp[4], c5 = sp[5], c6 = sp[6], c7 = sp[7];
            for (; it + 16 <= n; it += 8) {
                const int2 n0 = sp[it + 8],  n1 = sp[it + 9];
                const int2 n2 = sp[it + 10], n3 = sp[it + 11];
                const int2 n4 = sp[it + 12], n5 = sp[it + 13];
                const int2 n6 = sp[it + 14], n7 = sp[it + 15];
                s += x[(size_t)c0.y * D + f]; s += x[(size_t)c1.y * D + f];
                s += x[(size_t)c2.y * D + f]; s += x[(size_t)c3.y * D + f];
                s += x[(size_t)c4.y * D + f]; s += x[(size_t)c5.y * D + f];
                s += x[(size_t)c6.y * D + f]; s += x[(size_t)c7.y * D + f];
                ax += ea[(size_t)(lo ? c0.x : c1.x) * ED + fe];
                ax += ea[(size_t)(lo ? c2.x : c3.x) * ED + fe];
                ay += ea[(size_t)(lo ? c4.x : c5.x) * ED + fe];
                ay += ea[(size_t)(lo ? c6.x : c7.x) * ED + fe];
                c0 = n0; c1 = n1; c2 = n2; c3 = n3;
                c4 = n4; c5 = n5; c6 = n6; c7 = n7;
            }
            s += x[(size_t)c0.y * D + f]; s += x[(size_t)c1.y * D + f];
            s += x[(size_t)c2.y * D + f]; s += x[(size_t)c3.y * D + f];
            s += x[(size_t)c4.y * D + f]; s += x[(size_t)c5.y * D + f];
            s += x[(size_t)c6.y * D + f]; s += x[(size_t)c7.y * D + f];
            ax += ea[(size_t)(lo ? c0.x : c1.x) * ED + fe];
            ax += ea[(size_t)(lo ? c2.x : c3.x) * ED + fe];
            ay += ea[(size_t)(lo ? c4.x : c5.x) * ED + fe];
            ay += ea[(size_t)(lo ? c6.x : c7.x) * ED + fe];
            it += 8;
        }
        for (; it < n; ++it) {               // tail: 0..7 edges
            const int2 p = sp[it];
            s += x[(size_t)p.y * D + f];
            if (lo) ax += ea[(size_t)p.x * ED + fe];
        }
        pre[(size_t)node * D + f] = s;
        ax += ay;
        ax += __shfl_xor(ax, 32);            // even-edge + odd-edge halves
        if (lo) aggEA[(size_t)node * ED + fe] = ax;
    }
}

// ---------------------------------------------------------------------------
// MLP1 as tiled GEMM: h[64n x 64f] = [pre|aggEA] @ [W1;Wc] + deg*bec + b1.
// Every dynamic index targets LDS (spill-proof). BN stats fused in epilogue.
__global__ __launch_bounds__(256) void mlp1g_kernel(
    const float* __restrict__ pre, const float* __restrict__ aggEA,
    const int* __restrict__ off,
    const float* __restrict__ W1, const float* __restrict__ wc,
    const float* __restrict__ bec, const float* __restrict__ b1,
    float* __restrict__ h, float* __restrict__ sums, float* __restrict__ sumsq)
{
    __shared__ float As[64 * 100];   // [node][k] k:0-63 pre, 64-95 aggEA
    __shared__ float Bs[96 * 64];    // [k][f]
    __shared__ float4 sb1v[16];
    __shared__ float4 sbecv[16];
    __shared__ float sDeg[64];
    const int tid = threadIdx.x;
    const int base = blockIdx.x * 64;

    for (int i = tid; i < 64 * 16; i += 256)
        ((float4*)Bs)[i] = ((const float4*)W1)[i];
    for (int i = tid; i < 32 * 16; i += 256)
        ((float4*)Bs)[64 * 16 + i] = ((const float4*)wc)[i];
    if (tid < 16)      sb1v[tid] = ((const float4*)b1)[tid];
    else if (tid < 32) sbecv[tid - 16] = ((const float4*)bec)[tid - 16];
    if (tid < 64) {
        const int node = base + tid;
        sDeg[tid] = (node < N_NODES) ? (float)(off[node + 1] - off[node]) : 0.f;
    }
    #pragma unroll
    for (int r = 0; r < 4; ++r) {
        const int idx = tid + 256 * r;
        const int nl = idx >> 4, c4 = idx & 15;
        const bool v = (base + nl) < N_NODES;
        const float4 t = v ? ((const float4*)pre)[(size_t)(base + nl) * 16 + c4]
                           : make_float4(0.f, 0.f, 0.f, 0.f);
        *(float4*)&As[nl * 100 + c4 * 4] = t;
    }
    #pragma unroll
    for (int r = 0; r < 2; ++r) {
        const int idx = tid + 256 * r;
        const int nl = idx >> 3, c4 = idx & 7;
        const bool v = (base + nl) < N_NODES;
        const float4 t = v ? ((const float4*)aggEA)[(size_t)(base + nl) * 8 + c4]
                           : make_float4(0.f, 0.f, 0.f, 0.f);
        *(float4*)&As[nl * 100 + 64 + c4 * 4] = t;
    }
    __syncthreads();

    const int tx = tid & 15, ty = tid >> 4;
    const int r0 = ty * 4;
    const float4 bb = sb1v[tx];
    const float4 bc = sbecv[tx];
    float4 acc0, acc1, acc2, acc3;
    acc0.x = bb.x + sDeg[r0+0]*bc.x; acc0.y = bb.y + sDeg[r0+0]*bc.y;
    acc0.z = bb.z + sDeg[r0+0]*bc.z; acc0.w = bb.w + sDeg[r0+0]*bc.w;
    acc1.x = bb.x + sDeg[r0+1]*bc.x; acc1.y = bb.y + sDeg[r0+1]*bc.y;
    acc1.z = bb.z + sDeg[r0+1]*bc.z; acc1.w = bb.w + sDeg[r0+1]*bc.w;
    acc2.x = bb.x + sDeg[r0+2]*bc.x; acc2.y = bb.y + sDeg[r0+2]*bc.y;
    acc2.z = bb.z + sDeg[r0+2]*bc.z; acc2.w = bb.w + sDeg[r0+2]*bc.w;
    acc3.x = bb.x + sDeg[r0+3]*bc.x; acc3.y = bb.y + sDeg[r0+3]*bc.y;
    acc3.z = bb.z + sDeg[r0+3]*bc.z; acc3.w = bb.w + sDeg[r0+3]*bc.w;

    for (int k4 = 0; k4 < 24; ++k4) {
        const int k = k4 * 4;
        const float4 a0 = *(const float4*)&As[(r0+0)*100 + k];
        const float4 a1 = *(const float4*)&As[(r0+1)*100 + k];
        const float4 a2 = *(const float4*)&As[(r0+2)*100 + k];
        const float4 a3 = *(const float4*)&As[(r0+3)*100 + k];
        const float4 w0 = *(const float4*)&Bs[(k+0)*64 + tx*4];
        const float4 w1v = *(const float4*)&Bs[(k+1)*64 + tx*4];
        const float4 w2v = *(const float4*)&Bs[(k+2)*64 + tx*4];
        const float4 w3v = *(const float4*)&Bs[(k+3)*64 + tx*4];
        acc0.x += a0.x*w0.x + a0.y*w1v.x + a0.z*w2v.x + a0.w*w3v.x;
        acc0.y += a0.x*w0.y + a0.y*w1v.y + a0.z*w2v.y + a0.w*w3v.y;
        acc0.z += a0.x*w0.z + a0.y*w1v.z + a0.z*w2v.z + a0.w*w3v.z;
        acc0.w += a0.x*w0.w + a0.y*w1v.w + a0.z*w2v.w + a0.w*w3v.w;
        acc1.x += a1.x*w0.x + a1.y*w1v.x + a1.z*w2v.x + a1.w*w3v.x;
        acc1.y += a1.x*w0.y + a1.y*w1v.y + a1.z*w2v.y + a1.w*w3v.y;
        acc1.z += a1.x*w0.z + a1.y*w1v.z + a1.z*w2v.z + a1.w*w3v.z;
        acc1.w += a1.x*w0.w + a1.y*w1v.w + a1.z*w2v.w + a1.w*w3v.w;
        acc2.x += a2.x*w0.x + a2.y*w1v.x + a2.z*w2v.x + a2.w*w3v.x;
        acc2.y += a2.x*w0.y + a2.y*w1v.y + a2.z*w2v.y + a2.w*w3v.y;
        acc2.z += a2.x*w0.z + a2.y*w1v.z + a2.z*w2v.z + a2.w*w3v.z;
        acc2.w += a2.x*w0.w + a2.y*w1v.w + a2.z*w2v.w + a2.w*w3v.w;
        acc3.x += a3.x*w0.x + a3.y*w1v.x + a3.z*w2v.x + a3.w*w3v.x;
        acc3.y += a3.x*w0.y + a3.y*w1v.y + a3.z*w2v.y + a3.w*w3v.y;
        acc3.z += a3.x*w0.z + a3.y*w1v.z + a3.z*w2v.z + a3.w*w3v.z;
        acc3.w += a3.x*w0.w + a3.y*w1v.w + a3.z*w2v.w + a3.w*w3v.w;
    }

    float4 ps = make_float4(0.f, 0.f, 0.f, 0.f);
    float4 pq = make_float4(0.f, 0.f, 0.f, 0.f);
    {
        const int n0 = base + r0;
        if (n0 + 0 < N_NODES) {
            ((float4*)h)[(size_t)(n0+0)*16 + tx] = acc0;
            ps.x += acc0.x; ps.y += acc0.y; ps.z += acc0.z; ps.w += acc0.w;
            pq.x += acc0.x*acc0.x; pq.y += acc0.y*acc0.y;
            pq.z += acc0.z*acc0.z; pq.w += acc0.w*acc0.w;
        }
        if (n0 + 1 < N_NODES) {
            ((float4*)h)[(size_t)(n0+1)*16 + tx] = acc1;
            ps.x += acc1.x; ps.y += acc1.y; ps.z += acc1.z; ps.w += acc1.w;
            pq.x += acc1.x*acc1.x; pq.y += acc1.y*acc1.y;
            pq.z += acc1.z*acc1.z; pq.w += acc1.w*acc1.w;
        }
        if (n0 + 2 < N_NODES) {
            ((float4*)h)[(size_t)(n0+2)*16 + tx] = acc2;
            ps.x += acc2.x; ps.y += acc2.y; ps.z += acc2.z; ps.w += acc2.w;
            pq.x += acc2.x*acc2.x; pq.y += acc2.y*acc2.y;
            pq.z += acc2.z*acc2.z; pq.w += acc2.w*acc2.w;
        }
        if (n0 + 3 < N_NODES) {
            ((float4*)h)[(size_t)(n0+3)*16 + tx] = acc3;
            ps.x += acc3.x; ps.y += acc3.y; ps.z += acc3.z; ps.w += acc3.w;
            pq.x += acc3.x*acc3.x; pq.y += acc3.y*acc3.y;
            pq.z += acc3.z*acc3.z; pq.w += acc3.w*acc3.w;
        }
    }
    __syncthreads();
    float* sS = Bs;                 // reuse B-tile LDS for BN reduction
    float* sQ = Bs + 1024;
    sS[ty*64 + tx*4 + 0] = ps.x; sS[ty*64 + tx*4 + 1] = ps.y;
    sS[ty*64 + tx*4 + 2] = ps.z; sS[ty*64 + tx*4 + 3] = ps.w;
    sQ[ty*64 + tx*4 + 0] = pq.x; sQ[ty*64 + tx*4 + 1] = pq.y;
    sQ[ty*64 + tx*4 + 2] = pq.z; sQ[ty*64 + tx*4 + 3] = pq.w;
    __syncthreads();
    if (tid < 64) {
        float s = 0.f, q = 0.f;
        #pragma unroll
        for (int r = 0; r < 16; ++r) { s += sS[r*64 + tid]; q += sQ[r*64 + tid]; }
        unsafeAtomicAdd(&sums[tid], s);
        unsafeAtomicAdd(&sumsq[tid], q);
    }
}

// ---------------------------------------------------------------------------
// MLP2 as tiled GEMM: out = relu(h*sc+sh) @ W2 + b2 (BN applied at A-staging)
__global__ __launch_bounds__(256) void mlp2g_kernel(
    const float* __restrict__ h, const float* __restrict__ W2,
    const float* __restrict__ b2, const float* __restrict__ sums,
    const float* __restrict__ sumsq, const float* __restrict__ gamma,
    const float* __restrict__ beta, float* __restrict__ out)
{
    __shared__ float As[64 * 68];
    __shared__ float Bs[64 * 64];
    __shared__ float4 sb2v[16];
    __shared__ float4 sscv[16];
    __shared__ float4 sshv[16];
    const int tid = threadIdx.x;
    const int base = blockIdx.x * 64;

    for (int i = tid; i < 64 * 16; i += 256)
        ((float4*)Bs)[i] = ((const float4*)W2)[i];
    if (tid < 16) sb2v[tid] = ((const float4*)b2)[tid];
    if (tid < 64) {
        const float inv_n = 1.0f / (float)N_NODES;
        const float mean = sums[tid] * inv_n;
        const float var  = sumsq[tid] * inv_n - mean * mean;   // biased, like jnp.var
        const float sc   = gamma[tid] * rsqrtf(var + BN_EPS);
        ((float*)sscv)[tid] = sc;
        ((float*)sshv)[tid] = beta[tid] - mean * sc;
    }
    __syncthreads();

    #pragma unroll
    for (int r = 0; r < 4; ++r) {
        const int idx = tid + 256 * r;
        const int nl = idx >> 4, c4 = idx & 15;
        const bool v = (base + nl) < N_NODES;
        const float4 t = v ? ((const float4*)h)[(size_t)(base + nl) * 16 + c4]
                           : make_float4(0.f, 0.f, 0.f, 0.f);
        const float4 c = sscv[c4];
        const float4 s = sshv[c4];
        float4 rv;
        rv.x = fmaxf(t.x * c.x + s.x, 0.f);
        rv.y = fmaxf(t.y * c.y + s.y, 0.f);
        rv.z = fmaxf(t.z * c.z + s.z, 0.f);
        rv.w = fmaxf(t.w * c.w + s.w, 0.f);
        *(float4*)&As[nl * 68 + c4 * 4] = rv;
    }
    __syncthreads();

    const int tx = tid & 15, ty = tid >> 4;
    const int r0 = ty * 4;
    const float4 bb = sb2v[tx];
    float4 acc0 = bb, acc1 = bb, acc2 = bb, acc3 = bb;

    for (int k4 = 0; k4 < 16; ++k4) {
        const int k = k4 * 4;
        const float4 a0 = *(const float4*)&As[(r0+0)*68 + k];
        const float4 a1 = *(const float4*)&As[(r0+1)*68 + k];
        const float4 a2 = *(const float4*)&As[(r0+2)*68 + k];
        const float4 a3 = *(const float4*)&As[(r0+3)*68 + k];
        const float4 w0 = *(const float4*)&Bs[(k+0)*64 + tx*4];
        const float4 w1v = *(const float4*)&Bs[(k+1)*64 + tx*4];
        const float4 w2v = *(const float4*)&Bs[(k+2)*64 + tx*4];
        const float4 w3v = *(const float4*)&Bs[(k+3)*64 + tx*4];
        acc0.x += a0.x*w0.x + a0.y*w1v.x + a0.z*w2v.x + a0.w*w3v.x;
        acc0.y += a0.x*w0.y + a0.y*w1v.y + a0.z*w2v.y + a0.w*w3v.y;
        acc0.z += a0.x*w0.z + a0.y*w1v.z + a0.z*w2v.z + a0.w*w3v.z;
        acc0.w += a0.x*w0.w + a0.y*w1v.w + a0.z*w2v.w + a0.w*w3v.w;
        acc1.x += a1.x*w0.x + a1.y*w1v.x + a1.z*w2v.x + a1.w*w3v.x;
        acc1.y += a1.x*w0.y + a1.y*w1v.y + a1.z*w2v.y + a1.w*w3v.y;
        acc1.z += a1.x*w0.z + a1.y*w1v.z + a1.z*w2v.z + a1.w*w3v.z;
        acc1.w += a1.x*w0.w + a1.y*w1v.w + a1.z*w2v.w + a1.w*w3v.w;
        acc2.x += a2.x*w0.x + a2.y*w1v.x + a2.z*w2v.x + a2.w*w3v.x;
        acc2.y += a2.x*w0.y + a2.y*w1v.y + a2.z*w2v.y + a2.w*w3v.y;
        acc2.z += a2.x*w0.z + a2.y*w1v.z + a2.z*w2v.z + a2.w*w3v.z;
        acc2.w += a2.x*w0.w + a2.y*w1v.w + a2.z*w2v.w + a2.w*w3v.w;
        acc3.x += a3.x*w0.x + a3.y*w1v.x + a3.z*w2v.x + a3.w*w3v.x;
        acc3.y += a3.x*w0.y + a3.y*w1v.y + a3.z*w2v.y + a3.w*w3v.y;
        acc3.z += a3.x*w0.z + a3.y*w1v.z + a3.z*w2v.z + a3.w*w3v.z;
        acc3.w += a3.x*w0.w + a3.y*w1v.w + a3.z*w2v.w + a3.w*w3v.w;
    }

    const int n0 = base + r0;
    if (n0 + 0 < N_NODES) ((float4*)out)[(size_t)(n0+0)*16 + tx] = acc0;
    if (n0 + 1 < N_NODES) ((float4*)out)[(size_t)(n0+1)*16 + tx] = acc1;
    if (n0 + 2 < N_NODES) ((float4*)out)[(size_t)(n0+2)*16 + tx] = acc2;
    if (n0 + 3 < N_NODES) ((float4*)out)[(size_t)(n0+3)*16 + tx] = acc3;
}

// ---------------------------------------------------------------------------
extern "C" void kernel_launch(void* const* d_in, const int* in_sizes, int n_in,
                              void* d_out, int out_size, void* d_ws, size_t ws_size,
                              hipStream_t stream) {
    const float* x     = (const float*)d_in[0];
    const int*   ei    = (const int*)  d_in[1];   // [2, E] int32
    const float* ea    = (const float*)d_in[2];
    const float* We    = (const float*)d_in[3];
    const float* be    = (const float*)d_in[4];
    const float* W1    = (const float*)d_in[5];
    const float* b1    = (const float*)d_in[6];
    const float* gamma = (const float*)d_in[7];
    const float* beta  = (const float*)d_in[8];
    const float* W2    = (const float*)d_in[9];
    const float* b2    = (const float*)d_in[10];

    float* ws      = (float*)d_ws;
    float* sums    = ws + WS_SUMS;
    float* sumsq   = ws + WS_SUMSQ;
    int*   resv    = (int*)(ws + WS_RESV);
    int*   off     = (int*)(ws + WS_OFF);
    uint2* pack    = (uint2*)(ws + WS_PACK);
    int2*  sorted2 = (int2*)(ws + WS_SRC2);
    float* h       = ws + WS_H;
    float* wcbuf   = ws + WS_WC;
    float* becbuf  = ws + WS_BEC;

    float* pre     = (float*)d_out;  // reuse nothing risky: d_out sized N*D
    // NOTE: we still need separate pre/aggEA buffers; place after BEC.
    float* preb    = ws + (WS_BEC + 64);
    float* aggEA   = preb + (size_t)N_NODES * D;
    (void)pre;

    hipMemsetAsync(ws, 0, (size_t)WS_ZERO_END * sizeof(float), stream);

    bin_scatter_kernel <<<NB_SC + 8, 256, 0, stream>>>(ei, resv, pack,
                                                       We, W1, be, wcbuf, becbuf);
    bucket_place_kernel<<<NBKT, 512, 0, stream>>>(resv, pack, off, sorted2);
    agg_kernel         <<<2048, 256, 0, stream>>>(x, ea, off, sorted2, preb, aggEA);
    mlp1g_kernel       <<<N_BLK, 256, 0, stream>>>(preb, aggEA, off, W1, wcbuf,
                                                   becbuf, b1, h, sums, sumsq);
    mlp2g_kernel       <<<N_BLK, 256, 0, stream>>>(h, W2, b2, sums, sumsq,
                                                   gamma, beta, (float*)d_out);
}